// Round 4
// baseline (3561.031 us; speedup 1.0000x reference)
//
#include <hip/hip_runtime.h>
#include <hip/hip_cooperative_groups.h>

namespace cg = cooperative_groups;

// Problem constants (fixed by reference)
#define NN   50000
#define DD   16
#define FFE  256
#define HH   8
#define DHH  32
#define RR   20
#define HOPN 10

#define DIFF_BLOCKS 1024
#define NPB 49            // ceil(50000/1024) nodes per block

typedef unsigned short u16;
typedef unsigned int   u32;
typedef __attribute__((ext_vector_type(8))) short  short8;   // 8 bf16 = 4 VGPRs
typedef __attribute__((ext_vector_type(4))) float  floatx4;

__device__ __forceinline__ float b2f(u16 u){ return __uint_as_float(((u32)u)<<16); }
__device__ __forceinline__ u16 f2b(float f){
  u32 x = __float_as_uint(f);
  u32 r = (x + 0x7fffu + ((x>>16)&1u)) >> 16;   // RNE
  return (u16)r;
}

// ---------------------------------------------------------------------------
// castw: one-off cast+transpose of value-path weights to bf16 [N][K] layout.
// ---------------------------------------------------------------------------
__global__ __launch_bounds__(256) void castw_kernel(
    const float* __restrict__ We, const float* __restrict__ W1,
    const float* __restrict__ W2,
    u16* __restrict__ Wet, u16* __restrict__ W1t, u16* __restrict__ W2t)
{
  int tid = blockIdx.x*256 + threadIdx.x;
  if (tid < 256*256) {                       // W_ent [256][256] -> Wet[n][k]
    int k = tid >> 8, n = tid & 255;
    Wet[n*256 + k] = f2b(We[tid]);
  } else if (tid < 256*256 + 256*1024) {     // W1 [256][1024] -> W1t[n][k]
    int s = tid - 65536;
    int k = s >> 10, n = s & 1023;
    W1t[n*256 + k] = f2b(W1[s]);
  } else if (tid < 589824) {                 // W2 [1024][256] -> W2t[n][k]
    int s = tid - 327680;
    int k = s >> 8, n = s & 255;
    W2t[n*1024 + k] = f2b(W2[s]);
  }
}

// ---------------------------------------------------------------------------
// prep: blocks 0..19 -> LN(rel_feat[r]) @ W_rel -> er[r,h]  (fp64, selection)
//       block 20     -> fold attn into W: Wh2[k,h], Wt2[k,h]
// ---------------------------------------------------------------------------
__global__ __launch_bounds__(256) void prep_kernel(
    const float* __restrict__ rel_feat,
    const float* __restrict__ W_head, const float* __restrict__ W_tail,
    const float* __restrict__ W_rel,
    const float* __restrict__ attn_h, const float* __restrict__ attn_t,
    const float* __restrict__ attn_r,
    const float* __restrict__ lng, const float* __restrict__ lnb,
    double* __restrict__ Wh2, double* __restrict__ Wt2, double* __restrict__ er)
{
  int t = threadIdx.x;
  if (blockIdx.x == RR) {
    for (int h = 0; h < HH; h++) {
      double sh = 0.0, st = 0.0;
      #pragma unroll
      for (int c = 0; c < DHH; c++) {
        int j = h*DHH + c;
        sh += (double)W_head[t*FFE + j] * (double)attn_h[j];
        st += (double)W_tail[t*FFE + j] * (double)attn_t[j];
      }
      Wh2[t*HH + h] = sh;
      Wt2[t*HH + h] = st;
    }
    return;
  }
  int r = blockIdx.x;
  __shared__ double red[8];
  __shared__ double rln[256];
  double v = (double)rel_feat[r*FFE + t];
  double s = v, q = v*v;
  #pragma unroll
  for (int o = 32; o; o >>= 1) { s += __shfl_xor(s, o, 64); q += __shfl_xor(q, o, 64); }
  if ((t & 63) == 0) { red[t>>6] = s; red[4 + (t>>6)] = q; }
  __syncthreads();
  double stot = red[0]+red[1]+red[2]+red[3];
  double qtot = red[4]+red[5]+red[6]+red[7];
  double mean = stot * (1.0/256.0);
  double var  = qtot * (1.0/256.0) - mean*mean;
  double rstd = 1.0 / sqrt(var + 1e-5);
  rln[t] = (v - mean) * rstd * (double)lng[t] + (double)lnb[t];
  __syncthreads();
  double acc = 0.0;
  for (int k = 0; k < 256; k++) acc += rln[k] * (double)W_rel[k*FFE + t];
  double p = acc * (double)attn_r[t];
  #pragma unroll
  for (int o = 16; o; o >>= 1) p += __shfl_down(p, o, 32);
  if ((t & 31) == 0) er[r*HH + (t>>5)] = p;
}

// ---------------------------------------------------------------------------
// logits: per 16-node tile. LN(ent) in fp64 -> xb (bf16, value path) and
//         eh/et = x64 @ Wh2/Wt2 (fp64, selection path, 8-way ILP).
// ---------------------------------------------------------------------------
__global__ __launch_bounds__(256) void logits_kernel(
    const float* __restrict__ ent,
    const float* __restrict__ lng, const float* __restrict__ lnb,
    const double* __restrict__ Wh2, const double* __restrict__ Wt2,
    u16* __restrict__ xb, double* __restrict__ eh, double* __restrict__ et)
{
  __shared__ double xs[16][258];
  int tid = threadIdx.x;
  int i0 = blockIdx.x * 16;
  int wave = tid >> 6, lane = tid & 63;
  for (int m = wave; m < 16; m += 4) {
    int row = i0 + m;
    float4 u = *(const float4*)&ent[row*FFE + lane*4];
    double v0 = u.x, v1 = u.y, v2 = u.z, v3 = u.w;
    double s = v0+v1+v2+v3;
    double q = v0*v0 + v1*v1 + v2*v2 + v3*v3;
    #pragma unroll
    for (int o = 32; o; o >>= 1) { s += __shfl_xor(s, o, 64); q += __shfl_xor(q, o, 64); }
    double mean = s * (1.0/256.0);
    double var  = q * (1.0/256.0) - mean*mean;
    double rstd = 1.0 / sqrt(var + 1e-5);
    float4 ug = *(const float4*)&lng[lane*4];
    float4 ub = *(const float4*)&lnb[lane*4];
    double y0 = (v0-mean)*rstd*(double)ug.x + (double)ub.x;
    double y1 = (v1-mean)*rstd*(double)ug.y + (double)ub.y;
    double y2 = (v2-mean)*rstd*(double)ug.z + (double)ub.z;
    double y3 = (v3-mean)*rstd*(double)ug.w + (double)ub.w;
    int c = lane*4;
    xs[m][c] = y0; xs[m][c+1] = y1; xs[m][c+2] = y2; xs[m][c+3] = y3;
    ushort4 o4;
    o4.x = f2b((float)y0); o4.y = f2b((float)y1);
    o4.z = f2b((float)y2); o4.w = f2b((float)y3);
    *(ushort4*)&xb[row*FFE + c] = o4;
  }
  __syncthreads();
  // phase 2: one output per thread, 8 independent fp64 accumulators (ILP).
  int m = (tid & 127) >> 3, h = tid & 7;
  const double* __restrict__ Wp = (tid < 128) ? Wh2 : Wt2;
  double* __restrict__ op = (tid < 128) ? eh : et;
  double a0=0,a1=0,a2=0,a3=0,a4=0,a5=0,a6=0,a7=0;
  for (int k = 0; k < 256; k += 8) {
    a0 += xs[m][k+0] * Wp[(k+0)*HH + h];
    a1 += xs[m][k+1] * Wp[(k+1)*HH + h];
    a2 += xs[m][k+2] * Wp[(k+2)*HH + h];
    a3 += xs[m][k+3] * Wp[(k+3)*HH + h];
    a4 += xs[m][k+4] * Wp[(k+4)*HH + h];
    a5 += xs[m][k+5] * Wp[(k+5)*HH + h];
    a6 += xs[m][k+6] * Wp[(k+6)*HH + h];
    a7 += xs[m][k+7] * Wp[(k+7)*HH + h];
  }
  op[(i0+m)*HH + h] = ((a0+a1)+(a2+a3)) + ((a4+a5)+(a6+a7));
}

// ---------------------------------------------------------------------------
// gemm: C[M,N] = A[M,K]bf16 @ B[N,K]bf16 (B pre-transposed), MFMA 16x16x32.
// 128x128 tile, BK=32, 256 threads (4 waves, each 32 rows x 128 cols).
// EPI 0: bf16 store. EPI 1: relu(v+bias) bf16. EPI 2: v+bias+feat+ent fp32.
// ---------------------------------------------------------------------------
template<int EPI>
__global__ __launch_bounds__(256) void gemm_kernel(
    const u16* __restrict__ A, const u16* __restrict__ B,
    const float* __restrict__ bias,
    const u16* __restrict__ feat, const float* __restrict__ ent,
    u16* __restrict__ Obf, float* __restrict__ Of,
    int M, int N, int K)
{
  __shared__ u16 As[128][40];
  __shared__ u16 Bs[128][40];
  int t = threadIdx.x;
  int i0 = blockIdx.x * 128;
  int n0 = blockIdx.y * 128;
  int w = t >> 6, l = t & 63;
  int cr = t >> 2;              // staging row 0..63 (and +64)
  int cc = (t & 3) * 8;         // staging k-offset {0,8,16,24}
  int ga0 = min(i0 + cr, M-1);  // clamp M-boundary reads (stores predicated)
  int ga1 = min(i0 + cr + 64, M-1);
  int gb0 = n0 + cr;
  int gb1 = n0 + cr + 64;
  floatx4 acc[2][8];
  #pragma unroll
  for (int mt = 0; mt < 2; mt++)
    #pragma unroll
    for (int nt = 0; nt < 8; nt++) acc[mt][nt] = (floatx4){0.f,0.f,0.f,0.f};
  int ln = l & 15, lq = (l >> 4) * 8;
  for (int k0 = 0; k0 < K; k0 += 32) {
    __syncthreads();
    *(uint4*)&As[cr][cc]      = *(const uint4*)&A[(size_t)ga0*K + k0 + cc];
    *(uint4*)&As[cr+64][cc]   = *(const uint4*)&A[(size_t)ga1*K + k0 + cc];
    *(uint4*)&Bs[cr][cc]      = *(const uint4*)&B[(size_t)gb0*K + k0 + cc];
    *(uint4*)&Bs[cr+64][cc]   = *(const uint4*)&B[(size_t)gb1*K + k0 + cc];
    __syncthreads();
    short8 bfr[8];
    #pragma unroll
    for (int nt = 0; nt < 8; nt++) bfr[nt] = *(const short8*)&Bs[nt*16 + ln][lq];
    #pragma unroll
    for (int mt = 0; mt < 2; mt++) {
      short8 afr = *(const short8*)&As[w*32 + mt*16 + ln][lq];
      #pragma unroll
      for (int nt = 0; nt < 8; nt++)
        acc[mt][nt] = __builtin_amdgcn_mfma_f32_16x16x32_bf16(afr, bfr[nt], acc[mt][nt], 0, 0, 0);
    }
  }
  int lr = (l >> 4) * 4;        // C/D layout: col=lane&15, row=(lane>>4)*4+reg
  #pragma unroll
  for (int mt = 0; mt < 2; mt++) {
    #pragma unroll
    for (int nt = 0; nt < 8; nt++) {
      int col = n0 + nt*16 + ln;
      #pragma unroll
      for (int r = 0; r < 4; r++) {
        int row = i0 + w*32 + mt*16 + lr + r;
        if (row < M) {
          float v = acc[mt][nt][r];
          if (EPI == 0) {
            Obf[(size_t)row*N + col] = f2b(v);
          } else if (EPI == 1) {
            v += bias[col];
            Obf[(size_t)row*N + col] = f2b(v > 0.f ? v : 0.f);
          } else {
            v += bias[col] + b2f(feat[(size_t)row*FFE + col]) + ent[(size_t)row*FFE + col];
            Of[(size_t)row*N + col] = v;
          }
        }
      }
    }
  }
}

// ---------------------------------------------------------------------------
// edge: per (i,h): e_d = leaky(eh[src]+et+er[rid]) in fp64; top-5 (+1 tie slot);
//       weights = exp(e-max)/sum_top5, prescaled by (1-ALPHA)=0.9.
// ---------------------------------------------------------------------------
__global__ __launch_bounds__(256) void edge_kernel(
    const int* __restrict__ src, const int* __restrict__ rid,
    const double* __restrict__ eh, const double* __restrict__ et,
    const double* __restrict__ er,
    int* __restrict__ idx6, float* __restrict__ w6)
{
  int tid = blockIdx.x*256 + threadIdx.x;
  if (tid >= NN*HH) return;
  int i = tid >> 3, h = tid & 7;
  double bet = et[tid];
  double e[16]; int sj[16];
  #pragma unroll
  for (int d = 0; d < 16; d++) {
    int s = src[i*DD + d];
    int rv = rid[i*DD + d];
    sj[d] = s;
    double v = eh[s*HH + h] + bet + er[rv*HH + h];
    e[d] = (v > 0.0) ? v : 0.2 * v;
  }
  u32 mask = 0; double vs[5]; int js[5];
  #pragma unroll
  for (int k = 0; k < 5; k++) {
    double best = -1e300; int bj = 0, bd = 0;
    #pragma unroll
    for (int d = 0; d < 16; d++) {
      bool c = (((mask>>d)&1u) == 0u) && (e[d] > best);
      if (c) { best = e[d]; bj = sj[d]; bd = d; }
    }
    mask |= (1u << bd); vs[k] = best; js[k] = bj;
  }
  double kth = vs[4];
  int j6 = 0; bool f6 = false;
  #pragma unroll
  for (int d = 0; d < 16; d++) {
    if ((((mask>>d)&1u) == 0u) && (e[d] == kth) && !f6) { j6 = sj[d]; f6 = true; }
  }
  float m0 = (float)vs[0];
  float ex[5], ssum = 0.f;
  #pragma unroll
  for (int k = 0; k < 5; k++) { ex[k] = __expf((float)vs[k] - m0); ssum += ex[k]; }
  float inv = 0.9f / ssum;
  long base = (long)tid * 6;
  #pragma unroll
  for (int k = 0; k < 5; k++) { idx6[base+k] = js[k]; w6[base+k] = ex[k]*inv; }
  idx6[base+5] = j6; w6[base+5] = f6 ? ex[4]*inv : 0.f;
}

// ---------------------------------------------------------------------------
// diff_fused: all 10 hops in ONE cooperative dispatch.
// Grid 1024 x 256 (4 blocks/CU; co-residency cap is 8 from 18.4 KB LDS).
// idx/w loaded to LDS ONCE, reused all 10 hops. Ping-pong fA/fB in global,
// grid.sync + device fences between hops (per-XCD L2 non-coherence).
// ---------------------------------------------------------------------------
__global__ __launch_bounds__(256) void diff_fused_kernel(
    const u16* __restrict__ fe, u16* __restrict__ fA, u16* __restrict__ fB,
    const int* __restrict__ idx6, const float* __restrict__ w6)
{
  __shared__ int   sIdx[NPB*48];
  __shared__ float sW[NPB*48];
  int tid = threadIdx.x;
  int node0 = blockIdx.x * NPB;
  for (int s = tid; s < NPB*48; s += 256) {
    int node = node0 + s/48;
    if (node < NN) {
      sIdx[s] = idx6[(size_t)node*48 + (s%48)];
      sW[s]   = w6[(size_t)node*48 + (s%48)];
    } else { sIdx[s] = 0; sW[s] = 0.f; }
  }
  __syncthreads();
  int h = tid >> 5, c = tid & 31;
  cg::grid_group grid = cg::this_grid();
  const u16* cur = fe;
  for (int hop = 0; hop < HOPN; hop++) {
    u16* nxt = (hop & 1) ? fB : fA;
    for (int s = 0; s < NPB; s++) {
      int node = node0 + s;
      if (node < NN) {
        float acc = 0.1f * b2f(fe[(size_t)node*FFE + tid]);
        int base = s*48 + h*6;
        #pragma unroll
        for (int k = 0; k < 5; k++) {
          int j = sIdx[base+k];
          acc += sW[base+k] * b2f(cur[(size_t)j*FFE + h*DHH + c]);
        }
        float w5 = sW[base+5];
        if (w5 != 0.f) {                      // tie slot: rare, group-uniform
          int j = sIdx[base+5];
          acc += w5 * b2f(cur[(size_t)j*FFE + h*DHH + c]);
        }
        nxt[(size_t)node*FFE + tid] = f2b(acc);
      }
    }
    cur = nxt;
    __threadfence();      // release this hop's stores to device scope
    grid.sync();
    __threadfence();      // acquire: don't serve next hop's gathers stale
  }
}

// ---------------------------------------------------------------------------
// ln_ff: y = bf16( LN(feat+ent) ).  One wave per row, lane holds 4 elems.
// ---------------------------------------------------------------------------
__global__ __launch_bounds__(256) void ln_ff_kernel(
    const u16* __restrict__ feat, const float* __restrict__ ent,
    const float* __restrict__ g, const float* __restrict__ b,
    u16* __restrict__ y)
{
  int w = threadIdx.x >> 6, l = threadIdx.x & 63;
  int row = blockIdx.x*4 + w;
  float4 e4 = *(const float4*)&ent[row*FFE + l*4];
  ushort4 fv = *(const ushort4*)&feat[row*FFE + l*4];
  float v0 = b2f(fv.x)+e4.x, v1 = b2f(fv.y)+e4.y;
  float v2 = b2f(fv.z)+e4.z, v3 = b2f(fv.w)+e4.w;
  float s = v0+v1+v2+v3;
  float q = v0*v0 + v1*v1 + v2*v2 + v3*v3;
  #pragma unroll
  for (int o = 32; o; o >>= 1) { s += __shfl_xor(s, o, 64); q += __shfl_xor(q, o, 64); }
  float mean = s * (1.f/256.f);
  float var  = q * (1.f/256.f) - mean*mean;
  float rstd = rsqrtf(var + 1e-5f);
  float4 g4 = *(const float4*)&g[l*4];
  float4 b4 = *(const float4*)&b[l*4];
  ushort4 o4;
  o4.x = f2b((v0-mean)*rstd*g4.x + b4.x);
  o4.y = f2b((v1-mean)*rstd*g4.y + b4.y);
  o4.z = f2b((v2-mean)*rstd*g4.z + b4.z);
  o4.w = f2b((v3-mean)*rstd*g4.w + b4.w);
  *(ushort4*)&y[row*FFE + l*4] = o4;
}

// ---------------------------------------------------------------------------
extern "C" void kernel_launch(void* const* d_in, const int* in_sizes, int n_in,
                              void* d_out, int out_size, void* d_ws, size_t ws_size,
                              hipStream_t stream)
{
  const float* ent      = (const float*)d_in[0];
  const float* rel      = (const float*)d_in[1];
  const float* W_head   = (const float*)d_in[2];
  const float* W_tail   = (const float*)d_in[3];
  const float* W_ent    = (const float*)d_in[4];
  const float* W_rel    = (const float*)d_in[5];
  const float* attn_h   = (const float*)d_in[6];
  const float* attn_t   = (const float*)d_in[7];
  const float* attn_r   = (const float*)d_in[8];
  const float* ln_ent_g = (const float*)d_in[9];
  const float* ln_ent_b = (const float*)d_in[10];
  const float* ln_rel_g = (const float*)d_in[11];
  const float* ln_rel_b = (const float*)d_in[12];
  const float* ln_ff_g  = (const float*)d_in[13];
  const float* ln_ff_b  = (const float*)d_in[14];
  const float* W1       = (const float*)d_in[15];
  const float* b1       = (const float*)d_in[16];
  const float* W2       = (const float*)d_in[17];
  const float* b2       = (const float*)d_in[18];
  const int* src        = (const int*)d_in[19];
  const int* rid        = (const int*)d_in[20];
  float* out = (float*)d_out;

  // Workspace layout. h1 (102.4 MB) ALIASES [0, 102.4 MB): all tensors there
  // are dead before gemm1 runs (edge/diff/proj consumers all finished).
  char* w = (char*)d_ws;
  double* er64 = (double*)(w + 0);            // 1.3 KB   (dead after edge)
  double* Wh2  = (double*)(w + 4096);         // 16 KB    (dead after logits)
  double* Wt2  = (double*)(w + 20480);        // 16 KB
  double* eh64 = (double*)(w + 36864);        // 3.2 MB   (dead after edge)
  double* et64 = (double*)(w + 3236864);      // 3.2 MB
  u16*    xb   = (u16*)  (w + 6436864);       // 25.6 MB  (dead after proj)
  u16*    fe   = (u16*)  (w + 32036864);      // 25.6 MB  (dead after hops)
  u16*    fA   = (u16*)  (w + 57636864);      // 25.6 MB  (dead after hops)
  int*    idx6 = (int*)  (w + 83236864);      // 9.6 MB   (dead after hops)
  float*  w6   = (float*)(w + 92836864);      // 9.6 MB   (dead after hops)
  u16*    h1   = (u16*)  (w + 0);             // 102.4 MB alias, gemm1->gemm2
  u16*    fB   = (u16*)  (w + 102436864);     // 25.6 MB  (final feat, live to end)
  u16*    y    = (u16*)  (w + 128036864);     // 25.6 MB
  u16*    Wet  = (u16*)  (w + 153636864);     // 128 KB
  u16*    W1t  = (u16*)  (w + 153767936);     // 512 KB
  u16*    W2t  = (u16*)  (w + 154292224);     // 512 KB  (end 154,816,512)

  castw_kernel<<<2304, 256, 0, stream>>>(W_ent, W1, W2, Wet, W1t, W2t);
  prep_kernel<<<RR+1, 256, 0, stream>>>(rel, W_head, W_tail, W_rel,
                                        attn_h, attn_t, attn_r,
                                        ln_rel_g, ln_rel_b, Wh2, Wt2, er64);
  logits_kernel<<<NN/16, 256, 0, stream>>>(ent, ln_ent_g, ln_ent_b, Wh2, Wt2,
                                           xb, eh64, et64);
  // proj: fe = xb @ Wet
  {
    dim3 g((NN + 127)/128, 2);
    gemm_kernel<0><<<g, 256, 0, stream>>>(xb, Wet, nullptr, nullptr, nullptr,
                                          fe, nullptr, NN, 256, 256);
  }
  edge_kernel<<<(NN*HH + 255)/256, 256, 0, stream>>>(src, rid, eh64, et64, er64,
                                                     idx6, w6);
  // all 10 hops in one cooperative dispatch; result lands in fB (hop 9 odd)
  {
    void* args[] = { (void*)&fe, (void*)&fA, (void*)&fB,
                     (void*)&idx6, (void*)&w6 };
    hipLaunchCooperativeKernel((const void*)diff_fused_kernel,
                               dim3(DIFF_BLOCKS), dim3(256), args, 0, stream);
  }
  const u16* cur = fB;
  ln_ff_kernel<<<NN/4, 256, 0, stream>>>(cur, ent, ln_ff_g, ln_ff_b, y);
  {
    dim3 g((NN + 127)/128, 8);                 // h1 = relu(y@W1 + b1)
    gemm_kernel<1><<<g, 256, 0, stream>>>(y, W1t, b1, nullptr, nullptr,
                                          h1, nullptr, NN, 1024, 256);
  }
  {
    dim3 g((NN + 127)/128, 2);                 // out = h1@W2 + b2 + feat + ent
    gemm_kernel<2><<<g, 256, 0, stream>>>(h1, W2t, b2, cur, ent,
                                          nullptr, out, NN, 256, 1024);
  }
}

// Round 5
// 886.366 us; speedup vs baseline: 4.0176x; 4.0176x over previous
//
#include <hip/hip_runtime.h>

// Problem constants (fixed by reference)
#define NN   50000
#define DD   16
#define FFE  256
#define HH   8
#define DHH  32
#define RR   20
#define HOPN 10

typedef unsigned short u16;
typedef unsigned int   u32;
typedef __attribute__((ext_vector_type(8))) short  short8;   // 8 bf16 = 4 VGPRs
typedef __attribute__((ext_vector_type(4))) float  floatx4;

__device__ __forceinline__ float b2f(u16 u){ return __uint_as_float(((u32)u)<<16); }
__device__ __forceinline__ u16 f2b(float f){
  u32 x = __float_as_uint(f);
  u32 r = (x + 0x7fffu + ((x>>16)&1u)) >> 16;   // RNE
  return (u16)r;
}

// ---------------------------------------------------------------------------
// castw: one-off cast+transpose of value-path weights to bf16 [N][K] layout.
// ---------------------------------------------------------------------------
__global__ __launch_bounds__(256) void castw_kernel(
    const float* __restrict__ We, const float* __restrict__ W1,
    const float* __restrict__ W2,
    u16* __restrict__ Wet, u16* __restrict__ W1t, u16* __restrict__ W2t)
{
  int tid = blockIdx.x*256 + threadIdx.x;
  if (tid < 256*256) {                       // W_ent [256][256] -> Wet[n][k]
    int k = tid >> 8, n = tid & 255;
    Wet[n*256 + k] = f2b(We[tid]);
  } else if (tid < 256*256 + 256*1024) {     // W1 [256][1024] -> W1t[n][k]
    int s = tid - 65536;
    int k = s >> 10, n = s & 1023;
    W1t[n*256 + k] = f2b(W1[s]);
  } else if (tid < 589824) {                 // W2 [1024][256] -> W2t[n][k]
    int s = tid - 327680;
    int k = s >> 8, n = s & 255;
    W2t[n*1024 + k] = f2b(W2[s]);
  }
}

// ---------------------------------------------------------------------------
// prep: blocks 0..19 -> LN(rel_feat[r]) @ W_rel -> er[r,h]  (fp64, selection)
//       block 20     -> fold attn into W: Wh2[k,h], Wt2[k,h]
// ---------------------------------------------------------------------------
__global__ __launch_bounds__(256) void prep_kernel(
    const float* __restrict__ rel_feat,
    const float* __restrict__ W_head, const float* __restrict__ W_tail,
    const float* __restrict__ W_rel,
    const float* __restrict__ attn_h, const float* __restrict__ attn_t,
    const float* __restrict__ attn_r,
    const float* __restrict__ lng, const float* __restrict__ lnb,
    double* __restrict__ Wh2, double* __restrict__ Wt2, double* __restrict__ er)
{
  int t = threadIdx.x;
  if (blockIdx.x == RR) {
    for (int h = 0; h < HH; h++) {
      double sh = 0.0, st = 0.0;
      #pragma unroll
      for (int c = 0; c < DHH; c++) {
        int j = h*DHH + c;
        sh += (double)W_head[t*FFE + j] * (double)attn_h[j];
        st += (double)W_tail[t*FFE + j] * (double)attn_t[j];
      }
      Wh2[t*HH + h] = sh;
      Wt2[t*HH + h] = st;
    }
    return;
  }
  int r = blockIdx.x;
  __shared__ double red[8];
  __shared__ double rln[256];
  double v = (double)rel_feat[r*FFE + t];
  double s = v, q = v*v;
  #pragma unroll
  for (int o = 32; o; o >>= 1) { s += __shfl_xor(s, o, 64); q += __shfl_xor(q, o, 64); }
  if ((t & 63) == 0) { red[t>>6] = s; red[4 + (t>>6)] = q; }
  __syncthreads();
  double stot = red[0]+red[1]+red[2]+red[3];
  double qtot = red[4]+red[5]+red[6]+red[7];
  double mean = stot * (1.0/256.0);
  double var  = qtot * (1.0/256.0) - mean*mean;
  double rstd = 1.0 / sqrt(var + 1e-5);
  rln[t] = (v - mean) * rstd * (double)lng[t] + (double)lnb[t];
  __syncthreads();
  double acc = 0.0;
  for (int k = 0; k < 256; k++) acc += rln[k] * (double)W_rel[k*FFE + t];
  double p = acc * (double)attn_r[t];
  #pragma unroll
  for (int o = 16; o; o >>= 1) p += __shfl_down(p, o, 32);
  if ((t & 31) == 0) er[r*HH + (t>>5)] = p;
}

// ---------------------------------------------------------------------------
// logits: per 16-node tile. LN(ent) in fp64 -> xb (bf16, value path) and
//         eh/et = x64 @ Wh2/Wt2 (fp64, selection path, 8-way ILP).
// ---------------------------------------------------------------------------
__global__ __launch_bounds__(256) void logits_kernel(
    const float* __restrict__ ent,
    const float* __restrict__ lng, const float* __restrict__ lnb,
    const double* __restrict__ Wh2, const double* __restrict__ Wt2,
    u16* __restrict__ xb, double* __restrict__ eh, double* __restrict__ et)
{
  __shared__ double xs[16][258];
  int tid = threadIdx.x;
  int i0 = blockIdx.x * 16;
  int wave = tid >> 6, lane = tid & 63;
  for (int m = wave; m < 16; m += 4) {
    int row = i0 + m;
    float4 u = *(const float4*)&ent[row*FFE + lane*4];
    double v0 = u.x, v1 = u.y, v2 = u.z, v3 = u.w;
    double s = v0+v1+v2+v3;
    double q = v0*v0 + v1*v1 + v2*v2 + v3*v3;
    #pragma unroll
    for (int o = 32; o; o >>= 1) { s += __shfl_xor(s, o, 64); q += __shfl_xor(q, o, 64); }
    double mean = s * (1.0/256.0);
    double var  = q * (1.0/256.0) - mean*mean;
    double rstd = 1.0 / sqrt(var + 1e-5);
    float4 ug = *(const float4*)&lng[lane*4];
    float4 ub = *(const float4*)&lnb[lane*4];
    double y0 = (v0-mean)*rstd*(double)ug.x + (double)ub.x;
    double y1 = (v1-mean)*rstd*(double)ug.y + (double)ub.y;
    double y2 = (v2-mean)*rstd*(double)ug.z + (double)ub.z;
    double y3 = (v3-mean)*rstd*(double)ug.w + (double)ub.w;
    int c = lane*4;
    xs[m][c] = y0; xs[m][c+1] = y1; xs[m][c+2] = y2; xs[m][c+3] = y3;
    ushort4 o4;
    o4.x = f2b((float)y0); o4.y = f2b((float)y1);
    o4.z = f2b((float)y2); o4.w = f2b((float)y3);
    *(ushort4*)&xb[row*FFE + c] = o4;
  }
  __syncthreads();
  // phase 2: one output per thread, 8 independent fp64 accumulators (ILP).
  int m = (tid & 127) >> 3, h = tid & 7;
  const double* __restrict__ Wp = (tid < 128) ? Wh2 : Wt2;
  double* __restrict__ op = (tid < 128) ? eh : et;
  double a0=0,a1=0,a2=0,a3=0,a4=0,a5=0,a6=0,a7=0;
  for (int k = 0; k < 256; k += 8) {
    a0 += xs[m][k+0] * Wp[(k+0)*HH + h];
    a1 += xs[m][k+1] * Wp[(k+1)*HH + h];
    a2 += xs[m][k+2] * Wp[(k+2)*HH + h];
    a3 += xs[m][k+3] * Wp[(k+3)*HH + h];
    a4 += xs[m][k+4] * Wp[(k+4)*HH + h];
    a5 += xs[m][k+5] * Wp[(k+5)*HH + h];
    a6 += xs[m][k+6] * Wp[(k+6)*HH + h];
    a7 += xs[m][k+7] * Wp[(k+7)*HH + h];
  }
  op[(i0+m)*HH + h] = ((a0+a1)+(a2+a3)) + ((a4+a5)+(a6+a7));
}

// ---------------------------------------------------------------------------
// gemm: C[M,N] = A[M,K]bf16 @ B[N,K]bf16 (B pre-transposed), MFMA 16x16x32.
// 128x128 tile, BK=32, 256 threads (4 waves, each 32 rows x 128 cols).
// EPI 0: bf16 store. EPI 1: relu(v+bias) bf16. EPI 2: v+bias+feat+ent fp32.
// ---------------------------------------------------------------------------
template<int EPI>
__global__ __launch_bounds__(256) void gemm_kernel(
    const u16* __restrict__ A, const u16* __restrict__ B,
    const float* __restrict__ bias,
    const u16* __restrict__ feat, const float* __restrict__ ent,
    u16* __restrict__ Obf, float* __restrict__ Of,
    int M, int N, int K)
{
  __shared__ u16 As[128][40];
  __shared__ u16 Bs[128][40];
  int t = threadIdx.x;
  int i0 = blockIdx.x * 128;
  int n0 = blockIdx.y * 128;
  int w = t >> 6, l = t & 63;
  int cr = t >> 2;              // staging row 0..63 (and +64)
  int cc = (t & 3) * 8;         // staging k-offset {0,8,16,24}
  int ga0 = min(i0 + cr, M-1);  // clamp M-boundary reads (stores predicated)
  int ga1 = min(i0 + cr + 64, M-1);
  int gb0 = n0 + cr;
  int gb1 = n0 + cr + 64;
  floatx4 acc[2][8];
  #pragma unroll
  for (int mt = 0; mt < 2; mt++)
    #pragma unroll
    for (int nt = 0; nt < 8; nt++) acc[mt][nt] = (floatx4){0.f,0.f,0.f,0.f};
  int ln = l & 15, lq = (l >> 4) * 8;
  for (int k0 = 0; k0 < K; k0 += 32) {
    __syncthreads();
    *(uint4*)&As[cr][cc]      = *(const uint4*)&A[(size_t)ga0*K + k0 + cc];
    *(uint4*)&As[cr+64][cc]   = *(const uint4*)&A[(size_t)ga1*K + k0 + cc];
    *(uint4*)&Bs[cr][cc]      = *(const uint4*)&B[(size_t)gb0*K + k0 + cc];
    *(uint4*)&Bs[cr+64][cc]   = *(const uint4*)&B[(size_t)gb1*K + k0 + cc];
    __syncthreads();
    short8 bfr[8];
    #pragma unroll
    for (int nt = 0; nt < 8; nt++) bfr[nt] = *(const short8*)&Bs[nt*16 + ln][lq];
    #pragma unroll
    for (int mt = 0; mt < 2; mt++) {
      short8 afr = *(const short8*)&As[w*32 + mt*16 + ln][lq];
      #pragma unroll
      for (int nt = 0; nt < 8; nt++)
        acc[mt][nt] = __builtin_amdgcn_mfma_f32_16x16x32_bf16(afr, bfr[nt], acc[mt][nt], 0, 0, 0);
    }
  }
  int lr = (l >> 4) * 4;        // C/D layout: col=lane&15, row=(lane>>4)*4+reg
  #pragma unroll
  for (int mt = 0; mt < 2; mt++) {
    #pragma unroll
    for (int nt = 0; nt < 8; nt++) {
      int col = n0 + nt*16 + ln;
      #pragma unroll
      for (int r = 0; r < 4; r++) {
        int row = i0 + w*32 + mt*16 + lr + r;
        if (row < M) {
          float v = acc[mt][nt][r];
          if (EPI == 0) {
            Obf[(size_t)row*N + col] = f2b(v);
          } else if (EPI == 1) {
            v += bias[col];
            Obf[(size_t)row*N + col] = f2b(v > 0.f ? v : 0.f);
          } else {
            v += bias[col] + b2f(feat[(size_t)row*FFE + col]) + ent[(size_t)row*FFE + col];
            Of[(size_t)row*N + col] = v;
          }
        }
      }
    }
  }
}

// ---------------------------------------------------------------------------
// edge: per (i,h): e_d = leaky(eh[src]+et+er[rid]) in fp64; top-5 (+1 tie slot);
//       weights = exp(e-max)/sum_top5, prescaled by (1-ALPHA)=0.9.
// ---------------------------------------------------------------------------
__global__ __launch_bounds__(256) void edge_kernel(
    const int* __restrict__ src, const int* __restrict__ rid,
    const double* __restrict__ eh, const double* __restrict__ et,
    const double* __restrict__ er,
    int* __restrict__ idx6, float* __restrict__ w6)
{
  int tid = blockIdx.x*256 + threadIdx.x;
  if (tid >= NN*HH) return;
  int i = tid >> 3, h = tid & 7;
  double bet = et[tid];
  double e[16]; int sj[16];
  #pragma unroll
  for (int d = 0; d < 16; d++) {
    int s = src[i*DD + d];
    int rv = rid[i*DD + d];
    sj[d] = s;
    double v = eh[s*HH + h] + bet + er[rv*HH + h];
    e[d] = (v > 0.0) ? v : 0.2 * v;
  }
  u32 mask = 0; double vs[5]; int js[5];
  #pragma unroll
  for (int k = 0; k < 5; k++) {
    double best = -1e300; int bj = 0, bd = 0;
    #pragma unroll
    for (int d = 0; d < 16; d++) {
      bool c = (((mask>>d)&1u) == 0u) && (e[d] > best);
      if (c) { best = e[d]; bj = sj[d]; bd = d; }
    }
    mask |= (1u << bd); vs[k] = best; js[k] = bj;
  }
  double kth = vs[4];
  int j6 = 0; bool f6 = false;
  #pragma unroll
  for (int d = 0; d < 16; d++) {
    if ((((mask>>d)&1u) == 0u) && (e[d] == kth) && !f6) { j6 = sj[d]; f6 = true; }
  }
  float m0 = (float)vs[0];
  float ex[5], ssum = 0.f;
  #pragma unroll
  for (int k = 0; k < 5; k++) { ex[k] = __expf((float)vs[k] - m0); ssum += ex[k]; }
  float inv = 0.9f / ssum;
  long base = (long)tid * 6;
  #pragma unroll
  for (int k = 0; k < 5; k++) { idx6[base+k] = js[k]; w6[base+k] = ex[k]*inv; }
  idx6[base+5] = j6; w6[base+5] = f6 ? ex[4]*inv : 0.f;
}

// ---------------------------------------------------------------------------
// diff: one hop. feat_new = 0.9*sum_k w*feat_old[idx] + 0.1*fe. Block = node.
// 50000 blocks => massive memory-level parallelism (the round-4 fusion at
// 1024 blocks was 6x slower: 16 VGPRs, no outstanding loads). Tie slot
// (w==0) skipped: saves 1/6 of gather traffic, branch uniform per half-wave.
// ---------------------------------------------------------------------------
__global__ __launch_bounds__(256) void diff_kernel(
    const u16* __restrict__ fold, const u16* __restrict__ fe,
    const int* __restrict__ idx6, const float* __restrict__ w6,
    u16* __restrict__ fnew)
{
  int i = blockIdx.x, tid = threadIdx.x;
  int h = tid >> 5, c = tid & 31;
  long eb = ((long)i*HH + h) * 6;
  float acc = 0.1f * b2f(fe[i*FFE + tid]);
  #pragma unroll
  for (int k = 0; k < 5; k++) {
    int j = idx6[eb + k];
    float w = w6[eb + k];
    acc += w * b2f(fold[(size_t)j*FFE + h*DHH + c]);
  }
  float w5 = w6[eb + 5];
  if (w5 != 0.f) {
    int j = idx6[eb + 5];
    acc += w5 * b2f(fold[(size_t)j*FFE + h*DHH + c]);
  }
  fnew[i*FFE + tid] = f2b(acc);
}

// ---------------------------------------------------------------------------
// ln_ff: y = bf16( LN(feat+ent) ).  One wave per row, lane holds 4 elems.
// ---------------------------------------------------------------------------
__global__ __launch_bounds__(256) void ln_ff_kernel(
    const u16* __restrict__ feat, const float* __restrict__ ent,
    const float* __restrict__ g, const float* __restrict__ b,
    u16* __restrict__ y)
{
  int w = threadIdx.x >> 6, l = threadIdx.x & 63;
  int row = blockIdx.x*4 + w;
  float4 e4 = *(const float4*)&ent[row*FFE + l*4];
  ushort4 fv = *(const ushort4*)&feat[row*FFE + l*4];
  float v0 = b2f(fv.x)+e4.x, v1 = b2f(fv.y)+e4.y;
  float v2 = b2f(fv.z)+e4.z, v3 = b2f(fv.w)+e4.w;
  float s = v0+v1+v2+v3;
  float q = v0*v0 + v1*v1 + v2*v2 + v3*v3;
  #pragma unroll
  for (int o = 32; o; o >>= 1) { s += __shfl_xor(s, o, 64); q += __shfl_xor(q, o, 64); }
  float mean = s * (1.f/256.f);
  float var  = q * (1.f/256.f) - mean*mean;
  float rstd = rsqrtf(var + 1e-5f);
  float4 g4 = *(const float4*)&g[l*4];
  float4 b4 = *(const float4*)&b[l*4];
  ushort4 o4;
  o4.x = f2b((v0-mean)*rstd*g4.x + b4.x);
  o4.y = f2b((v1-mean)*rstd*g4.y + b4.y);
  o4.z = f2b((v2-mean)*rstd*g4.z + b4.z);
  o4.w = f2b((v3-mean)*rstd*g4.w + b4.w);
  *(ushort4*)&y[row*FFE + l*4] = o4;
}

// ---------------------------------------------------------------------------
extern "C" void kernel_launch(void* const* d_in, const int* in_sizes, int n_in,
                              void* d_out, int out_size, void* d_ws, size_t ws_size,
                              hipStream_t stream)
{
  const float* ent      = (const float*)d_in[0];
  const float* rel      = (const float*)d_in[1];
  const float* W_head   = (const float*)d_in[2];
  const float* W_tail   = (const float*)d_in[3];
  const float* W_ent    = (const float*)d_in[4];
  const float* W_rel    = (const float*)d_in[5];
  const float* attn_h   = (const float*)d_in[6];
  const float* attn_t   = (const float*)d_in[7];
  const float* attn_r   = (const float*)d_in[8];
  const float* ln_ent_g = (const float*)d_in[9];
  const float* ln_ent_b = (const float*)d_in[10];
  const float* ln_rel_g = (const float*)d_in[11];
  const float* ln_rel_b = (const float*)d_in[12];
  const float* ln_ff_g  = (const float*)d_in[13];
  const float* ln_ff_b  = (const float*)d_in[14];
  const float* W1       = (const float*)d_in[15];
  const float* b1       = (const float*)d_in[16];
  const float* W2       = (const float*)d_in[17];
  const float* b2       = (const float*)d_in[18];
  const int* src        = (const int*)d_in[19];
  const int* rid        = (const int*)d_in[20];
  float* out = (float*)d_out;

  // Workspace layout. h1 (102.4 MB) ALIASES [0, 102.4 MB): all tensors there
  // are dead before gemm1 runs (edge/diff/proj consumers all finished).
  // fB (final feat) lives OUTSIDE the alias region.
  char* w = (char*)d_ws;
  double* er64 = (double*)(w + 0);            // 1.3 KB   (dead after edge)
  double* Wh2  = (double*)(w + 4096);         // 16 KB    (dead after logits)
  double* Wt2  = (double*)(w + 20480);        // 16 KB
  double* eh64 = (double*)(w + 36864);        // 3.2 MB   (dead after edge)
  double* et64 = (double*)(w + 3236864);      // 3.2 MB
  u16*    xb   = (u16*)  (w + 6436864);       // 25.6 MB  (dead after proj)
  u16*    fe   = (u16*)  (w + 32036864);      // 25.6 MB  (dead after hops)
  u16*    fA   = (u16*)  (w + 57636864);      // 25.6 MB  (dead after hops)
  int*    idx6 = (int*)  (w + 83236864);      // 9.6 MB   (dead after hops)
  float*  w6   = (float*)(w + 92836864);      // 9.6 MB   (dead after hops)
  u16*    h1   = (u16*)  (w + 0);             // 102.4 MB alias, gemm1->gemm2
  u16*    fB   = (u16*)  (w + 102436864);     // 25.6 MB  (final feat, live to end)
  u16*    y    = (u16*)  (w + 128036864);     // 25.6 MB
  u16*    Wet  = (u16*)  (w + 153636864);     // 128 KB
  u16*    W1t  = (u16*)  (w + 153767936);     // 512 KB
  u16*    W2t  = (u16*)  (w + 154292224);     // 512 KB  (end 154,816,512)

  castw_kernel<<<2304, 256, 0, stream>>>(W_ent, W1, W2, Wet, W1t, W2t);
  prep_kernel<<<RR+1, 256, 0, stream>>>(rel, W_head, W_tail, W_rel,
                                        attn_h, attn_t, attn_r,
                                        ln_rel_g, ln_rel_b, Wh2, Wt2, er64);
  logits_kernel<<<NN/16, 256, 0, stream>>>(ent, ln_ent_g, ln_ent_b, Wh2, Wt2,
                                           xb, eh64, et64);
  // proj: fe = xb @ Wet
  {
    dim3 g((NN + 127)/128, 2);
    gemm_kernel<0><<<g, 256, 0, stream>>>(xb, Wet, nullptr, nullptr, nullptr,
                                          fe, nullptr, NN, 256, 256);
  }
  edge_kernel<<<(NN*HH + 255)/256, 256, 0, stream>>>(src, rid, eh64, et64, er64,
                                                     idx6, w6);
  // 10 hops, one dispatch each: 50000 blocks => latency hiding via TLP.
  const u16* cur = fe;
  u16* bufs[2] = { fA, fB };
  for (int hop = 0; hop < HOPN; hop++) {
    u16* nxt = bufs[hop & 1];
    diff_kernel<<<NN, 256, 0, stream>>>(cur, fe, idx6, w6, nxt);
    cur = nxt;                                 // final cur == fB (10 hops)
  }
  ln_ff_kernel<<<NN/4, 256, 0, stream>>>(cur, ent, ln_ff_g, ln_ff_b, y);
  {
    dim3 g((NN + 127)/128, 8);                 // h1 = relu(y@W1 + b1)
    gemm_kernel<1><<<g, 256, 0, stream>>>(y, W1t, b1, nullptr, nullptr,
                                          h1, nullptr, NN, 1024, 256);
  }
  {
    dim3 g((NN + 127)/128, 2);                 // out = h1@W2 + b2 + feat + ent
    gemm_kernel<2><<<g, 256, 0, stream>>>(h1, W2t, b2, cur, ent,
                                          nullptr, out, NN, 256, 1024);
  }
}